// Round 1
// 255.915 us; speedup vs baseline: 1.0114x; 1.0114x over previous
//
#include <hip/hip_runtime.h>
#include <hip/hip_bf16.h>

#define T_DIM 200
#define U_DIM 100
#define U1    101
#define H_DIM 320
#define K_INNER 512
#define V_DIM 1000
#define B_DIM 4
#define ND 300            // diagonals d = t+u in [0, 299]
#define ROWS 48           // 12 t x 4 u per block
#define XPITCH 520        // 512 fp8 + 8B pad: conflict-free + imm-offset addressable
#define CHUNK 8           // dp: diagonals per LDS chunk

typedef unsigned short ushort_t;
typedef unsigned char uchar_t;
typedef unsigned int uint32;
typedef long lfrag;       // 8 x fp8 = 2 VGPRs

typedef float ffrag4 __attribute__((ext_vector_type(4)));

#define LOG2E   1.4426950408889634f
#define LOG2E16 (1.4426950408889634f * 0.0625f)   // LOG2E/16 (W2 packed with x16 scale)
#define LN2     0.6931471805599453f

__device__ __forceinline__ float tanh_fast(float x) {
  float e = __expf(2.0f * x);                 // inf-safe: e=inf -> 1, e=0 -> -1
  return 1.0f - __fdividef(2.0f, e + 1.0f);
}

__device__ __forceinline__ uint2 pk_fp8x8(float t0, float t1, float t2, float t3,
                                          float t4, float t5, float t6, float t7) {
  uint2 r;
  r.x = (uint32)__builtin_amdgcn_cvt_pk_fp8_f32(t0, t1, 0, false);
  r.x = (uint32)__builtin_amdgcn_cvt_pk_fp8_f32(t2, t3, (int)r.x, true);
  r.y = (uint32)__builtin_amdgcn_cvt_pk_fp8_f32(t4, t5, 0, false);
  r.y = (uint32)__builtin_amdgcn_cvt_pk_fp8_f32(t6, t7, (int)r.y, true);
  return r;
}

// lane i <- lane i-1 (wave_shr:1 DPP, VALU-speed); invalid lane 0 gets `oldv`
__device__ __forceinline__ float dpp_up1(float v, float oldv) {
  return __int_as_float(__builtin_amdgcn_update_dpp(
      __float_as_int(oldv), __float_as_int(v), 0x138, 0xf, 0xf, false));
}

// ---------------- fused prep:
//   blocks [0,100):   h_enc projection (8 rows each)
//   blocks [100,151): h_dec projection (8 rows each)
//   blocks [151,215): W2 transpose-pack (x16 scale) into DMA-tile layout:
//     byte offset(kc, n) = (ct*16+ks)*8192 + w*2048 + q*512 + col*8
//     where ks=kc>>2, q=kc&3, ct=n>>8, w=(n>>6)&3, col=n&63.
//     Tile (ct,ks) = exactly the 8KB a joint block consumes per K-step, laid out
//     so each wave's 2KB slice is contiguous in lane-DMA order.
__global__ __launch_bounds__(512)
void prep_kernel(const float* __restrict__ enc, const float* __restrict__ dec,
                 const float* __restrict__ W1, const float* __restrict__ W2,
                 float* __restrict__ hEnc, float* __restrict__ hDec,
                 uchar_t* __restrict__ W2f8)
{
  __shared__ union { float sIn[8][H_DIM]; float sW[8][1024]; } sh;
  const int tid = threadIdx.x;
  const int blk = blockIdx.x;

  if (blk < 151) {
    const float* inp; float* outp; int nRows, rowOff, b0;
    if (blk < 100) { inp = enc; outp = hEnc; nRows = B_DIM * T_DIM; rowOff = 0;     b0 = blk; }
    else           { inp = dec; outp = hDec; nRows = B_DIM * U1;    rowOff = H_DIM; b0 = blk - 100; }
    const int r0 = b0 * 8;
    for (int i = tid; i < 8 * H_DIM; i += 512) {
      int r = i / H_DIM, k = i - r * H_DIM;
      int rr = r0 + r;
      sh.sIn[r][k] = (rr < nRows) ? inp[(size_t)rr * H_DIM + k] : 0.0f;
    }
    __syncthreads();
    const int c = tid;  // 0..511
    float acc[8];
#pragma unroll
    for (int r = 0; r < 8; ++r) acc[r] = 0.0f;
    const float* Wp = W1 + (size_t)rowOff * K_INNER + c;
    for (int k = 0; k < H_DIM; k += 4) {
      float w0 = Wp[(size_t)(k + 0) * K_INNER];
      float w1 = Wp[(size_t)(k + 1) * K_INNER];
      float w2 = Wp[(size_t)(k + 2) * K_INNER];
      float w3 = Wp[(size_t)(k + 3) * K_INNER];
#pragma unroll
      for (int r = 0; r < 8; ++r) {
        float4 s = *(const float4*)&sh.sIn[r][k];
        acc[r] = fmaf(s.w, w3, fmaf(s.z, w2, fmaf(s.y, w1, fmaf(s.x, w0, acc[r]))));
      }
    }
#pragma unroll
    for (int r = 0; r < 8; ++r) {
      int rr = r0 + r;
      if (rr < nRows) outp[(size_t)rr * K_INNER + c] = acc[r];
    }
  } else {
    // W2 pack: kchunk kc covers k in [kc*8, kc*8+8); LDS transpose; x16 scale
    // (raw |w| <= 0.045 sits in e4m3's denormal zone; x16 -> +-0.71, normal)
    const int kc = blk - 151;
    for (int i = tid; i < 8 * 1024; i += 512) {
      int r = i >> 10, n = i & 1023;
      sh.sW[r][n] = (n < V_DIM) ? W2[(size_t)(kc * 8 + r) * V_DIM + n] : 0.0f;
    }
    __syncthreads();
    const int ks = kc >> 2, q = kc & 3;
#pragma unroll
    for (int h = 0; h < 2; ++h) {
      int n = tid + h * 512;
      uint2 pk = pk_fp8x8(sh.sW[0][n] * 16.f, sh.sW[1][n] * 16.f,
                          sh.sW[2][n] * 16.f, sh.sW[3][n] * 16.f,
                          sh.sW[4][n] * 16.f, sh.sW[5][n] * 16.f,
                          sh.sW[6][n] * 16.f, sh.sW[7][n] * 16.f);
      const int ct = n >> 8, w = (n >> 6) & 3, col = n & 63;
      const size_t off = (size_t)(ct * 16 + ks) * 8192 + w * 2048 + q * 512 + col * 8;
      *(uint2*)&W2f8[off] = pk;
    }
  }
}

// ---------------- fused joint, fp8, 48-row tile, (256,3).
// K-loop B-feed: per-wave global_load_lds TRIPLE-buffer, 2 stages in flight
// (r10): with the r9 1-deep pipeline MfmaUtil sat at ~33% -- the vmcnt(2)
// cover (one iteration) is shorter than L2 latency under 12-wave contention.
// Now: issue tile g+2 while computing tile g, wait vmcnt(4) (= stages g+1,g+2
// outstanding). ct loop fully unrolled so the mod-3 buffer index is a
// compile-time constant (runtime-indexed -> scratch, rule #20). The first two
// stages are issued BEFORE the X-staging barrier so the W2 tile-0/1 fetch
// overlaps the tanh/pack phase; the barrier drains vmcnt(0) so in-loop vmcnt
// accounting sees only the loop's own DMA issues (b2/tokens also preloaded
// pre-barrier for the same reason).
__global__ __launch_bounds__(256, 3)
void joint_kernel(const float* __restrict__ hEnc, const float* __restrict__ hDec,
                  const float* __restrict__ b1, const uchar_t* __restrict__ W2f8,
                  const float* __restrict__ b2, const int* __restrict__ tokens,
                  float* __restrict__ pD)
{
  __shared__ union SU {
    uchar_t X[ROWS * XPITCH];     // 48 x 520 = 24,960 B
    float red[4][ROWS][4];
  } sh;
  __shared__ __align__(16) uchar_t sB[4][3][2048];   // per-wave B triple buffer (24KB)

  const int tid = threadIdx.x;
  const int b  = blockIdx.z;
  const int t0 = blockIdx.y * 12;   // 17 blocks cover 200 (writes guarded)
  const int u0 = blockIdx.x * 4;    // 26 blocks cover 104 >= 101
  const int wave = tid >> 6;
  const int lane = tid & 63;
  const int l15 = lane & 15;
  const int quad = lane >> 4;

  uchar_t* sBw = &sB[wave][0][0];
  const uchar_t* gW = W2f8 + (size_t)wave * 2048 + (size_t)lane * 16;

#define STAGE(gbase, bufv)                                                          \
  {                                                                                 \
    __builtin_amdgcn_global_load_lds(                                               \
        (const __attribute__((address_space(1))) void*)(gbase),                     \
        (__attribute__((address_space(3))) void*)(sBw + (bufv) * 2048, 16, 0, 0);   \
  }

#undef STAGE
#define STAGE(gbase, bufv)                                                          \
  {                                                                                 \
    __builtin_amdgcn_global_load_lds(                                               \
        (const __attribute__((address_space(1))) void*)(gbase),                     \
        (__attribute__((address_space(3))) void*)(sBw + (bufv) * 2048), 16, 0, 0);  \
    __builtin_amdgcn_global_load_lds(                                               \
        (const __attribute__((address_space(1))) void*)((gbase) + 1024),            \
        (__attribute__((address_space(3))) void*)(sBw + (bufv) * 2048 + 1024), 16, 0, 0); \
  }

  // issue tiles 0,1 immediately: they fly under the whole X-staging phase and
  // retire at the staging barrier (which drains vmcnt(0)).
  STAGE(gW, 0)
  STAGE(gW + 8192, 1)

  // preload b2 (scaled) + tokens to regs; they retire at the staging barrier
  float b2s[4][4];
#pragma unroll
  for (int ct = 0; ct < 4; ++ct)
#pragma unroll
    for (int cb = 0; cb < 4; ++cb) {
      int v = ct * 256 + wave * 64 + cb * 16 + l15;
      b2s[ct][cb] = (v < V_DIM) ? b2[v] * LOG2E : -1e30f;
    }
  int tokv[4];
#pragma unroll
  for (int j = 0; j < 4; ++j)
    tokv[j] = (u0 + j < U_DIM) ? tokens[b * U_DIM + u0 + j] : -1;

  // ---- X staging: per pass a wave owns one row; G = lane -> conflict-free
  for (int i = tid; i < ROWS * 64; i += 256) {
    const int row = i >> 6;           // 0..47
    const int G = i & 63;
    const int tcl = min(t0 + (row >> 2), T_DIM - 1);
    const int ucl = min(u0 + (row & 3), U1 - 1);
    const float* er = hEnc + (size_t)(b * T_DIM + tcl) * K_INNER;
    const float* dr = hDec + (size_t)(b * U1 + ucl) * K_INNER;
    const int k = G << 3;
    float4 e0 = *(const float4*)(er + k);
    float4 e1 = *(const float4*)(er + k + 4);
    float4 d0 = *(const float4*)(dr + k);
    float4 d1 = *(const float4*)(dr + k + 4);
    float4 c0 = *(const float4*)(b1 + k);
    float4 c1 = *(const float4*)(b1 + k + 4);
    uint2 pk = pk_fp8x8(tanh_fast(e0.x + d0.x + c0.x), tanh_fast(e0.y + d0.y + c0.y),
                        tanh_fast(e0.z + d0.z + c0.z), tanh_fast(e0.w + d0.w + c0.w),
                        tanh_fast(e1.x + d1.x + c1.x), tanh_fast(e1.y + d1.y + c1.y),
                        tanh_fast(e1.z + d1.z + c1.z), tanh_fast(e1.w + d1.w + c1.w));
    *(uint2*)&sh.X[row * XPITCH + (G << 3)] = pk;
  }
  __syncthreads();   // drains vmcnt(0): all loads above retired; buf 0,1 resident

  const uchar_t* aB = &sh.X[l15 * XPITCH + quad * 8];   // loop-invariant A base
  const uchar_t* bL = sBw + quad * 512 + l15 * 8;       // loop-invariant B base

  float sumexp[3][4], labelA[3][4], blankV[3][4];
#pragma unroll
  for (int i = 0; i < 3; ++i)
#pragma unroll
    for (int j = 0; j < 4; ++j) { sumexp[i][j] = 0.0f; labelA[i][j] = 0.0f; blankV[i][j] = 0.0f; }

#pragma unroll
  for (int ct = 0; ct < 4; ++ct) {
    ffrag4 acc[3][4];
    ffrag4 zero4 = {0.0f, 0.0f, 0.0f, 0.0f};
#pragma unroll
    for (int rb = 0; rb < 3; ++rb)
#pragma unroll
      for (int cb = 0; cb < 4; ++cb) acc[rb][cb] = zero4;

#pragma unroll
    for (int ks = 0; ks < 16; ++ks) {
      const int g = ct * 16 + ks;          // global tile index 0..63 (constexpr)
      if (g <= 61) {                       // keep 2 stages in flight
        STAGE(gW + (size_t)(g + 2) * 8192, (g + 2) % 3)
      }
      lfrag av[3];                         // A reads don't depend on B: issue
#pragma unroll                             // them under the in-flight DMA
      for (int rb = 0; rb < 3; ++rb)
        av[rb] = *(const lfrag*)(aB + rb * (16 * XPITCH) + ks * 32);
      if (g <= 61) {
        asm volatile("s_waitcnt vmcnt(4)" ::: "memory");   // stage g resident
      } else if (g == 62) {
        asm volatile("s_waitcnt vmcnt(2)" ::: "memory");
      } else {
        asm volatile("s_waitcnt vmcnt(0)" ::: "memory");
      }
      lfrag bv[4];
#pragma unroll
      for (int cb = 0; cb < 4; ++cb)
        bv[cb] = *(const lfrag*)(bL + (g % 3) * 2048 + cb * 128);
#pragma unroll
      for (int rb = 0; rb < 3; ++rb)
#pragma unroll
        for (int cb = 0; cb < 4; ++cb)
          acc[rb][cb] = __builtin_amdgcn_mfma_f32_16x16x32_fp8_fp8(av[rb], bv[cb], acc[rb][cb], 0, 0, 0);
    }

    // epilogue: acc = 16 x true logit (W2 scale); registers only (no vmem).
    // With the 2-deep pipeline, tiles for the next ct are already in flight
    // while this runs -- the epilogue doubles as latency cover.
#pragma unroll
    for (int cb = 0; cb < 4; ++cb) {
      const int v = ct * 256 + wave * 64 + cb * 16 + l15;
      const float bs = b2s[ct][cb];
#pragma unroll
      for (int rb = 0; rb < 3; ++rb)
#pragma unroll
        for (int reg = 0; reg < 4; ++reg) {
          float a = acc[rb][cb][reg];
          sumexp[rb][reg] += exp2f(fmaf(a, LOG2E16, bs));
          labelA[rb][reg] += (v == tokv[reg]) ? a : 0.0f;
        }
    }
    if (ct == 0 && wave == 0) {   // v==0 column lives on l15==0 lanes of cb 0
#pragma unroll
      for (int rb = 0; rb < 3; ++rb)
#pragma unroll
        for (int reg = 0; reg < 4; ++reg) blankV[rb][reg] = acc[rb][0][reg];
    }
  }
#undef STAGE

#pragma unroll
  for (int mask = 1; mask <= 8; mask <<= 1) {
#pragma unroll
    for (int rb = 0; rb < 3; ++rb)
#pragma unroll
      for (int reg = 0; reg < 4; ++reg) {
        sumexp[rb][reg] += __shfl_xor(sumexp[rb][reg], mask, 64);
        labelA[rb][reg] += __shfl_xor(labelA[rb][reg], mask, 64);
      }
  }

  __syncthreads();   // X reads done -> reuse union as red[]
  if (l15 == 0) {
#pragma unroll
    for (int rb = 0; rb < 3; ++rb)
#pragma unroll
      for (int reg = 0; reg < 4; ++reg) {
        int row = rb * 16 + quad * 4 + reg;
        sh.red[wave][row][0] = sumexp[rb][reg];
        sh.red[wave][row][1] = blankV[rb][reg];
        sh.red[wave][row][2] = labelA[rb][reg];
      }
  }
  __syncthreads();
  if (tid < ROWS) {
    float S  = sh.red[0][tid][0] + sh.red[1][tid][0] + sh.red[2][tid][0] + sh.red[3][tid][0];
    float Bl = sh.red[0][tid][1] + sh.red[1][tid][1] + sh.red[2][tid][1] + sh.red[3][tid][1];
    float Lb = sh.red[0][tid][2] + sh.red[1][tid][2] + sh.red[2][tid][2] + sh.red[3][tid][2];
    int t = t0 + (tid >> 2);
    int u = u0 + (tid & 3);
    if (t < T_DIM && u < U1) {
      float lse2 = __log2f(S);                 // S = sum(exp(true logit))
      int tok = (u < U_DIM) ? tokens[b * U_DIM + u] : 0;
      int d = t + u;
      size_t idx = (((size_t)b * ND + d) * 128 + u) * 2;
      pD[idx]     = fmaf(Bl, LOG2E16, b2[0]   * LOG2E) - lse2;   // blank
      pD[idx + 1] = fmaf(Lb, LOG2E16, b2[tok] * LOG2E) - lse2;   // label
    }
  }
}

// ---------------- RNNT DP, log2 domain, LDS-staged triple-buffered chunks.
// r9 residual (~100us, ~330cyc/step): per-step ds_read latency sat on the serial
// chain. Fix: batch all 8 q-reads of a chunk into registers (unrolled float4
// qv[8]) before the 8-step chain -- LDS latency paid once per chunk.
__global__ __launch_bounds__(256)
void dp_kernel(const float* __restrict__ pD,
               const int* __restrict__ outLen, const int* __restrict__ tokLen,
               float* __restrict__ outLoss)
{
  __shared__ __align__(16) float sD[4][3][CHUNK * 256];   // 96 KB triple buffer
  __shared__ float llsh[B_DIM];
  const int tid = threadIdx.x;
  const int wv = tid >> 6;                  // wave = batch
  const int lane = tid & 63;
  const float* src = pD + (size_t)wv * ND * 256;
  const int tIdx = outLen[wv] - 1;
  const int uIdx = tokLen[wv];
  const int dStar = tIdx + uIdx;
  const float NEG = -1e30f;
  const float blkStar = src[((size_t)dStar * 128 + uIdx) * 2];

  float aE = (lane == 0) ? 0.0f : NEG;      // log2 domain
  float aO = NEG;
  float ll2 = 0.0f;
  if (dStar == 0 && lane == 0) ll2 = blkStar;

  const int uE = 2 * lane;

#define ISSUE(c, buf)                                                         \
  {                                                                           \
    const float* g_ = src + (size_t)(c) * (CHUNK * 256);                      \
    float* l_ = &sD[wv][(buf)][0];                                            \
    _Pragma("unroll")                                                         \
    for (int j_ = 0; j_ < CHUNK; ++j_)                                        \
      __builtin_amdgcn_global_load_lds(                                       \
        (const __attribute__((address_space(1))) void*)(g_ + j_ * 256 + lane * 4), \
        (__attribute__((address_space(3))) void*)(l_ + j_ * 256), 16, 0, 0);  \
  }

  ISSUE(0, 0)
  ISSUE(1, 1)
#pragma unroll 1
  for (int c = 0; c < 38; ++c) {
    { const int nc = c + 2; const int cc = nc <= 37 ? nc : 37; ISSUE(cc, nc % 3) }
    asm volatile("s_waitcnt vmcnt(16)" ::: "memory");   // chunk c resident
    const float* buf = &sD[wv][c % 3][0];
    float4 qv[CHUNK];
#pragma unroll
    for (int j = 0; j < CHUNK; ++j)
      qv[j] = *(const float4*)&buf[j * 256 + uE * 2];
#pragma unroll
    for (int j = 0; j < CHUNK; ++j) {
      const int d = c * CHUNK + 1 + j;
      float4 q = qv[j];
      // q = (B[uE], L[uE], B[uE+1], L[uE+1]) at source diag d-1
      float aO_up = dpp_up1(aO, NEG);
      float labUp = dpp_up1(q.w, NEG);                // L[uE-1] @ d-1
      // uE cell
      float bt0 = aE + q.x, lt0 = aO_up + labUp;
      float mx0 = fmaxf(bt0, lt0), mn0 = fminf(bt0, lt0);
      float r0 = mx0 + __log2f(1.0f + exp2f(mn0 - mx0));
      int te = d - uE;
      float nE = ((uE <= U_DIM) && (te >= 0) && (te < T_DIM)) ? r0 : NEG;
      // uO cell
      float bt1 = aO + q.z, lt1 = aE + q.y;
      float mx1 = fmaxf(bt1, lt1), mn1 = fminf(bt1, lt1);
      float r1 = mx1 + __log2f(1.0f + exp2f(mn1 - mx1));
      int to = te - 1;
      float nO = ((uE + 1 <= U_DIM) && (to >= 0) && (to < T_DIM)) ? r1 : NEG;
      aE = nE; aO = nO;
      if (d == dStar) {
        if (uIdx == uE)          ll2 = nE + blkStar;
        else if (uIdx == uE + 1) ll2 = nO + blkStar;
      }
    }
  }
#undef ISSUE

#pragma unroll
  for (int mask = 1; mask < 64; mask <<= 1) ll2 += __shfl_xor(ll2, mask, 64);
  if (lane == 0) llsh[wv] = ll2;
  __syncthreads();
  if (tid == 0)
    outLoss[0] = -(llsh[0] + llsh[1] + llsh[2] + llsh[3]) * 0.25f * LN2;
}

// ---------------- launch
extern "C" void kernel_launch(void* const* d_in, const int* in_sizes, int n_in,
                              void* d_out, int out_size, void* d_ws, size_t ws_size,
                              hipStream_t stream)
{
  const float* enc    = (const float*)d_in[0];
  const float* dec    = (const float*)d_in[1];
  const int*   tokens = (const int*)d_in[2];
  const int*   outLen = (const int*)d_in[3];
  const int*   tokLen = (const int*)d_in[4];
  const float* W1     = (const float*)d_in[5];
  const float* b1     = (const float*)d_in[6];
  const float* W2     = (const float*)d_in[7];
  const float* b2     = (const float*)d_in[8];
  float* out = (float*)d_out;

  char* ws = (char*)d_ws;
  float*   hEnc = (float*)(ws + 0);           // 800*512*4     = 1,638,400
  float*   hDec = (float*)(ws + 1638400);     // 404*512*4     =   827,392
  uchar_t* W2f8 = (uchar_t*)(ws + 2465792);   // 64 tiles*8192 =   524,288 (16-aligned)
  float*   pD   = (float*)(ws + 2990080);     // 4*300*128*2*4 = 1,228,800
                                              // + 16KB tail pad for dp chunk-37 overread

  prep_kernel<<<dim3(215), dim3(512), 0, stream>>>(enc, dec, W1, W2, hEnc, hDec, W2f8);
  joint_kernel<<<dim3(26, 17, B_DIM), dim3(256), 0, stream>>>(hEnc, hDec, b1, W2f8, b2, tokens, pD);
  dp_kernel<<<dim3(1), dim3(256), 0, stream>>>(pD, outLen, tokLen, out);
}

// Round 2
// 246.926 us; speedup vs baseline: 1.0482x; 1.0364x over previous
//
#include <hip/hip_runtime.h>
#include <hip/hip_bf16.h>

#define T_DIM 200
#define U_DIM 100
#define U1    101
#define H_DIM 320
#define K_INNER 512
#define V_DIM 1000
#define B_DIM 4
#define ND 300            // diagonals d = t+u in [0, 299]
#define ROWS 48           // 12 t x 4 u per block
#define XPITCH 520        // 512 fp8 + 8B pad: conflict-free + imm-offset addressable
#define CHUNK 8           // dp: diagonals per LDS chunk

typedef unsigned short ushort_t;
typedef unsigned char uchar_t;
typedef unsigned int uint32;
typedef long lfrag;       // 8 x fp8 = 2 VGPRs

typedef float ffrag4 __attribute__((ext_vector_type(4)));
typedef int   ifrag  __attribute__((ext_vector_type(8)));   // 32 x fp8 = 8 VGPRs

#define LOG2E   1.4426950408889634f
#define LOG2E16 (1.4426950408889634f * 0.0625f)   // LOG2E/16 (W2 packed with x16 scale)
#define LN2     0.6931471805599453f

__device__ __forceinline__ float tanh_fast(float x) {
  float e = __expf(2.0f * x);                 // inf-safe: e=inf -> 1, e=0 -> -1
  return 1.0f - __fdividef(2.0f, e + 1.0f);
}

__device__ __forceinline__ uint2 pk_fp8x8(float t0, float t1, float t2, float t3,
                                          float t4, float t5, float t6, float t7) {
  uint2 r;
  r.x = (uint32)__builtin_amdgcn_cvt_pk_fp8_f32(t0, t1, 0, false);
  r.x = (uint32)__builtin_amdgcn_cvt_pk_fp8_f32(t2, t3, (int)r.x, true);
  r.y = (uint32)__builtin_amdgcn_cvt_pk_fp8_f32(t4, t5, 0, false);
  r.y = (uint32)__builtin_amdgcn_cvt_pk_fp8_f32(t6, t7, (int)r.y, true);
  return r;
}

// lane i <- lane i-1 (wave_shr:1 DPP, VALU-speed); invalid lane 0 gets `oldv`
__device__ __forceinline__ float dpp_up1(float v, float oldv) {
  return __int_as_float(__builtin_amdgcn_update_dpp(
      __float_as_int(oldv), __float_as_int(v), 0x138, 0xf, 0xf, false));
}

// ---------------- fused prep:
//   blocks [0,100):   h_enc projection (8 rows each)
//   blocks [100,151): h_dec projection (8 rows each)
//   blocks [151,215): W2 transpose-pack (x16 scale) for DIRECT-TO-REG loads in
//     the MX-scaled joint K-loop. Region index R(ct,ks4,w,cb) = ct*64+ks4*16+
//     w*4+cb -> 2KB, two coalesced 1KB halves (part = k-within-block / 16):
//       off = R*2048 + part*1024 + lane*16 + (k&15),  lane = quad*16+l15
//     so lane (quad,l15) assembles its v8i32 B fragment (col = cb*16+l15,
//     k = ks4*128 + quad*32 + 0..31) from two dwordx4 loads at +0 / +1024.
__global__ __launch_bounds__(512)
void prep_kernel(const float* __restrict__ enc, const float* __restrict__ dec,
                 const float* __restrict__ W1, const float* __restrict__ W2,
                 float* __restrict__ hEnc, float* __restrict__ hDec,
                 uchar_t* __restrict__ W2f8)
{
  __shared__ union { float sIn[8][H_DIM]; float sW[8][1024]; } sh;
  const int tid = threadIdx.x;
  const int blk = blockIdx.x;

  if (blk < 151) {
    const float* inp; float* outp; int nRows, rowOff, b0;
    if (blk < 100) { inp = enc; outp = hEnc; nRows = B_DIM * T_DIM; rowOff = 0;     b0 = blk; }
    else           { inp = dec; outp = hDec; nRows = B_DIM * U1;    rowOff = H_DIM; b0 = blk - 100; }
    const int r0 = b0 * 8;
    for (int i = tid; i < 8 * H_DIM; i += 512) {
      int r = i / H_DIM, k = i - r * H_DIM;
      int rr = r0 + r;
      sh.sIn[r][k] = (rr < nRows) ? inp[(size_t)rr * H_DIM + k] : 0.0f;
    }
    __syncthreads();
    const int c = tid;  // 0..511
    float acc[8];
#pragma unroll
    for (int r = 0; r < 8; ++r) acc[r] = 0.0f;
    const float* Wp = W1 + (size_t)rowOff * K_INNER + c;
    for (int k = 0; k < H_DIM; k += 4) {
      float w0 = Wp[(size_t)(k + 0) * K_INNER];
      float w1 = Wp[(size_t)(k + 1) * K_INNER];
      float w2 = Wp[(size_t)(k + 2) * K_INNER];
      float w3 = Wp[(size_t)(k + 3) * K_INNER];
#pragma unroll
      for (int r = 0; r < 8; ++r) {
        float4 s = *(const float4*)&sh.sIn[r][k];
        acc[r] = fmaf(s.w, w3, fmaf(s.z, w2, fmaf(s.y, w1, fmaf(s.x, w0, acc[r]))));
      }
    }
#pragma unroll
    for (int r = 0; r < 8; ++r) {
      int rr = r0 + r;
      if (rr < nRows) outp[(size_t)rr * K_INNER + c] = acc[r];
    }
  } else {
    // W2 pack: kchunk kc covers k in [kc*8, kc*8+8); LDS transpose; x16 scale
    // (raw |w| <= 0.045 sits in e4m3's denormal zone; x16 -> +-0.71, normal)
    const int kc = blk - 151;
    for (int i = tid; i < 8 * 1024; i += 512) {
      int r = i >> 10, n = i & 1023;
      sh.sW[r][n] = (n < V_DIM) ? W2[(size_t)(kc * 8 + r) * V_DIM + n] : 0.0f;
    }
    __syncthreads();
    // k = kc*8 + r:  ks4 = k>>7, quad = (k>>5)&3, i = k&31, part = i>>4, io = i&15
    const int ks4 = kc >> 4, qd = (kc >> 2) & 3, part = (kc >> 1) & 1, io = (kc & 1) * 8;
#pragma unroll
    for (int h = 0; h < 2; ++h) {
      int n = tid + h * 512;
      uint2 pk = pk_fp8x8(sh.sW[0][n] * 16.f, sh.sW[1][n] * 16.f,
                          sh.sW[2][n] * 16.f, sh.sW[3][n] * 16.f,
                          sh.sW[4][n] * 16.f, sh.sW[5][n] * 16.f,
                          sh.sW[6][n] * 16.f, sh.sW[7][n] * 16.f);
      const int ct = n >> 8, w = (n >> 6) & 3, cb = (n >> 4) & 3, l15 = n & 15;
      const int R = ct * 64 + ks4 * 16 + w * 4 + cb;
      const size_t off = (size_t)R * 2048 + part * 1024 + (qd * 16 + l15) * 16 + io;
      *(uint2*)&W2f8[off] = pk;
    }
  }
}

// ---------------- fused joint, MX-scaled fp8 (16x16x128, unity e8m0 scales),
// 48-row tile, (256,2).
// r11: non-scaled fp8 capped the MFMA pipe at ~44us ideal (2047 TF); the
// scaled K=128 intrinsic runs 2x (4661 TF) and cuts MFMA instructions 4x.
// B no longer fits an LDS pipeline at K=128 (8KB/wave/step), and it is
// stream-once + L2-resident (512KB) -> load B DIRECTLY TO REGISTERS
// (8 x dwordx4 per step, reg double-buffer, counted vmcnt(8)); sB/DMA deleted.
// A stays in LDS (4x reuse across ct), read as 4 x b64 per fragment.
__global__ __launch_bounds__(256, 2)
void joint_kernel(const float* __restrict__ hEnc, const float* __restrict__ hDec,
                  const float* __restrict__ b1, const uchar_t* __restrict__ W2f8,
                  const float* __restrict__ b2, const int* __restrict__ tokens,
                  float* __restrict__ pD)
{
  __shared__ union SU {
    uchar_t X[ROWS * XPITCH];     // 48 x 520 = 24,960 B
    float red[4][ROWS][4];
  } sh;

  const int tid = threadIdx.x;
  const int b  = blockIdx.z;
  const int t0 = blockIdx.y * 12;   // 17 blocks cover 200 (writes guarded)
  const int u0 = blockIdx.x * 4;    // 26 blocks cover 104 >= 101
  const int wave = tid >> 6;
  const int lane = tid & 63;
  const int l15 = lane & 15;
  const int quad = lane >> 4;

  // per-wave global B base: region R = g*16 + wave*4 + cb, lane-major 16B
  const uchar_t* gB = W2f8 + (size_t)wave * 8192 + (size_t)lane * 16;
  ifrag bv[2][4];                   // B reg double-buffer (64 VGPR)

#define LOADB(g_, s_)                                                        \
  {                                                                          \
    _Pragma("unroll")                                                        \
    for (int cb_ = 0; cb_ < 4; ++cb_) {                                      \
      const uchar_t* p_ = gB + (size_t)((g_) * 16 + cb_) * 2048;             \
      *(int4*)&bv[s_][cb_]       = *(const int4*)p_;                         \
      *((int4*)&bv[s_][cb_] + 1) = *(const int4*)(p_ + 1024);                \
    }                                                                        \
  }

  // preload b2 (scaled) + tokens to regs
  float b2s[4][4];
#pragma unroll
  for (int ct = 0; ct < 4; ++ct)
#pragma unroll
    for (int cb = 0; cb < 4; ++cb) {
      int v = ct * 256 + wave * 64 + cb * 16 + l15;
      b2s[ct][cb] = (v < V_DIM) ? b2[v] * LOG2E : -1e30f;
    }
  int tokv[4];
#pragma unroll
  for (int j = 0; j < 4; ++j)
    tokv[j] = (u0 + j < U_DIM) ? tokens[b * U_DIM + u0 + j] : -1;

  // ---- X staging: per pass a wave owns one row; G = lane -> conflict-free
  for (int i = tid; i < ROWS * 64; i += 256) {
    const int row = i >> 6;           // 0..47
    const int G = i & 63;
    const int tcl = min(t0 + (row >> 2), T_DIM - 1);
    const int ucl = min(u0 + (row & 3), U1 - 1);
    const float* er = hEnc + (size_t)(b * T_DIM + tcl) * K_INNER;
    const float* dr = hDec + (size_t)(b * U1 + ucl) * K_INNER;
    const int k = G << 3;
    float4 e0 = *(const float4*)(er + k);
    float4 e1 = *(const float4*)(er + k + 4);
    float4 d0 = *(const float4*)(dr + k);
    float4 d1 = *(const float4*)(dr + k + 4);
    float4 c0 = *(const float4*)(b1 + k);
    float4 c1 = *(const float4*)(b1 + k + 4);
    uint2 pk = pk_fp8x8(tanh_fast(e0.x + d0.x + c0.x), tanh_fast(e0.y + d0.y + c0.y),
                        tanh_fast(e0.z + d0.z + c0.z), tanh_fast(e0.w + d0.w + c0.w),
                        tanh_fast(e1.x + d1.x + c1.x), tanh_fast(e1.y + d1.y + c1.y),
                        tanh_fast(e1.z + d1.z + c1.z), tanh_fast(e1.w + d1.w + c1.w));
    *(uint2*)&sh.X[row * XPITCH + (G << 3)] = pk;
  }

  // issue step-0 B loads: overlap the barrier (worst case drained there; then
  // the in-loop vmcnt(8) accounting is still correct -- it counts newest-8)
  LOADB(0, 0)
  __syncthreads();

  // A base: lane (l15,quad) holds row l15, k = ks4*128 + quad*32 + 0..31
  const uchar_t* aB = &sh.X[l15 * XPITCH + quad * 32];

  float sumexp[3][4], labelA[3][4], blankV[3][4];
#pragma unroll
  for (int i = 0; i < 3; ++i)
#pragma unroll
    for (int j = 0; j < 4; ++j) { sumexp[i][j] = 0.0f; labelA[i][j] = 0.0f; blankV[i][j] = 0.0f; }

  union AF { ifrag f; lfrag q[4]; };

#pragma unroll
  for (int ct = 0; ct < 4; ++ct) {
    ffrag4 acc[3][4];
    ffrag4 zero4 = {0.0f, 0.0f, 0.0f, 0.0f};
#pragma unroll
    for (int rb = 0; rb < 3; ++rb)
#pragma unroll
      for (int cb = 0; cb < 4; ++cb) acc[rb][cb] = zero4;

#pragma unroll
    for (int ks4 = 0; ks4 < 4; ++ks4) {
      const int g = ct * 4 + ks4;      // 0..15 (constexpr: both loops unrolled)
      const int slot = ks4 & 1;        // == g&1 since ct*4 is even
      if (g < 15) LOADB(g + 1, slot ^ 1)
      AF av[3];                        // A ds_reads overlap the B wait
#pragma unroll
      for (int rb = 0; rb < 3; ++rb) {
        const uchar_t* ap = aB + rb * (16 * XPITCH) + ks4 * 128;
        av[rb].q[0] = *(const lfrag*)(ap);
        av[rb].q[1] = *(const lfrag*)(ap + 8);
        av[rb].q[2] = *(const lfrag*)(ap + 16);
        av[rb].q[3] = *(const lfrag*)(ap + 24);
      }
      if (g < 15) { asm volatile("s_waitcnt vmcnt(8)" ::: "memory"); }   // step g resident
      else        { asm volatile("s_waitcnt vmcnt(0)" ::: "memory"); }
#pragma unroll
      for (int rb = 0; rb < 3; ++rb)
#pragma unroll
        for (int cb = 0; cb < 4; ++cb)
          acc[rb][cb] = __builtin_amdgcn_mfma_scale_f32_16x16x128_f8f6f4(
              av[rb].f, bv[slot][cb], acc[rb][cb],
              0, 0,                     // cbsz/blgp: fp8 e4m3 / fp8 e4m3
              0, 0x7f7f7f7f,            // A scales: e8m0 127 = x1.0
              0, 0x7f7f7f7f);           // B scales: x1.0
    }

    // epilogue: acc = 16 x true logit (W2 scale); registers only (no vmem).
    // Next ct's first B loads are already in flight -> free latency cover.
#pragma unroll
    for (int cb = 0; cb < 4; ++cb) {
      const int v = ct * 256 + wave * 64 + cb * 16 + l15;
      const float bs = b2s[ct][cb];
#pragma unroll
      for (int rb = 0; rb < 3; ++rb)
#pragma unroll
        for (int reg = 0; reg < 4; ++reg) {
          float a = acc[rb][cb][reg];
          sumexp[rb][reg] += exp2f(fmaf(a, LOG2E16, bs));
          labelA[rb][reg] += (v == tokv[reg]) ? a : 0.0f;
        }
    }
    if (ct == 0 && wave == 0) {   // v==0 column lives on l15==0 lanes of cb 0
#pragma unroll
      for (int rb = 0; rb < 3; ++rb)
#pragma unroll
        for (int reg = 0; reg < 4; ++reg) blankV[rb][reg] = acc[rb][0][reg];
    }
  }
#undef LOADB

#pragma unroll
  for (int mask = 1; mask <= 8; mask <<= 1) {
#pragma unroll
    for (int rb = 0; rb < 3; ++rb)
#pragma unroll
      for (int reg = 0; reg < 4; ++reg) {
        sumexp[rb][reg] += __shfl_xor(sumexp[rb][reg], mask, 64);
        labelA[rb][reg] += __shfl_xor(labelA[rb][reg], mask, 64);
      }
  }

  __syncthreads();   // X reads done -> reuse union as red[]
  if (l15 == 0) {
#pragma unroll
    for (int rb = 0; rb < 3; ++rb)
#pragma unroll
      for (int reg = 0; reg < 4; ++reg) {
        int row = rb * 16 + quad * 4 + reg;
        sh.red[wave][row][0] = sumexp[rb][reg];
        sh.red[wave][row][1] = blankV[rb][reg];
        sh.red[wave][row][2] = labelA[rb][reg];
      }
  }
  __syncthreads();
  if (tid < ROWS) {
    float S  = sh.red[0][tid][0] + sh.red[1][tid][0] + sh.red[2][tid][0] + sh.red[3][tid][0];
    float Bl = sh.red[0][tid][1] + sh.red[1][tid][1] + sh.red[2][tid][1] + sh.red[3][tid][1];
    float Lb = sh.red[0][tid][2] + sh.red[1][tid][2] + sh.red[2][tid][2] + sh.red[3][tid][2];
    int t = t0 + (tid >> 2);
    int u = u0 + (tid & 3);
    if (t < T_DIM && u < U1) {
      float lse2 = __log2f(S);                 // S = sum(exp(true logit))
      int tok = (u < U_DIM) ? tokens[b * U_DIM + u] : 0;
      int d = t + u;
      size_t idx = (((size_t)b * ND + d) * 128 + u) * 2;
      pD[idx]     = fmaf(Bl, LOG2E16, b2[0]   * LOG2E) - lse2;   // blank
      pD[idx + 1] = fmaf(Lb, LOG2E16, b2[tok] * LOG2E) - lse2;   // label
    }
  }
}

// ---------------- RNNT DP, log2 domain, LDS-staged triple-buffered chunks.
// r9 residual (~100us, ~330cyc/step): per-step ds_read latency sat on the serial
// chain. Fix: batch all 8 q-reads of a chunk into registers (unrolled float4
// qv[8]) before the 8-step chain -- LDS latency paid once per chunk.
__global__ __launch_bounds__(256)
void dp_kernel(const float* __restrict__ pD,
               const int* __restrict__ outLen, const int* __restrict__ tokLen,
               float* __restrict__ outLoss)
{
  __shared__ __align__(16) float sD[4][3][CHUNK * 256];   // 96 KB triple buffer
  __shared__ float llsh[B_DIM];
  const int tid = threadIdx.x;
  const int wv = tid >> 6;                  // wave = batch
  const int lane = tid & 63;
  const float* src = pD + (size_t)wv * ND * 256;
  const int tIdx = outLen[wv] - 1;
  const int uIdx = tokLen[wv];
  const int dStar = tIdx + uIdx;
  const float NEG = -1e30f;
  const float blkStar = src[((size_t)dStar * 128 + uIdx) * 2];

  float aE = (lane == 0) ? 0.0f : NEG;      // log2 domain
  float aO = NEG;
  float ll2 = 0.0f;
  if (dStar == 0 && lane == 0) ll2 = blkStar;

  const int uE = 2 * lane;

#define ISSUE(c, buf)                                                         \
  {                                                                           \
    const float* g_ = src + (size_t)(c) * (CHUNK * 256);                      \
    float* l_ = &sD[wv][(buf)][0];                                            \
    _Pragma("unroll")                                                         \
    for (int j_ = 0; j_ < CHUNK; ++j_)                                        \
      __builtin_amdgcn_global_load_lds(                                       \
        (const __attribute__((address_space(1))) void*)(g_ + j_ * 256 + lane * 4), \
        (__attribute__((address_space(3))) void*)(l_ + j_ * 256), 16, 0, 0);  \
  }

  ISSUE(0, 0)
  ISSUE(1, 1)
#pragma unroll 1
  for (int c = 0; c < 38; ++c) {
    { const int nc = c + 2; const int cc = nc <= 37 ? nc : 37; ISSUE(cc, nc % 3) }
    asm volatile("s_waitcnt vmcnt(16)" ::: "memory");   // chunk c resident
    const float* buf = &sD[wv][c % 3][0];
    float4 qv[CHUNK];
#pragma unroll
    for (int j = 0; j < CHUNK; ++j)
      qv[j] = *(const float4*)&buf[j * 256 + uE * 2];
#pragma unroll
    for (int j = 0; j < CHUNK; ++j) {
      const int d = c * CHUNK + 1 + j;
      float4 q = qv[j];
      // q = (B[uE], L[uE], B[uE+1], L[uE+1]) at source diag d-1
      float aO_up = dpp_up1(aO, NEG);
      float labUp = dpp_up1(q.w, NEG);                // L[uE-1] @ d-1
      // uE cell
      float bt0 = aE + q.x, lt0 = aO_up + labUp;
      float mx0 = fmaxf(bt0, lt0), mn0 = fminf(bt0, lt0);
      float r0 = mx0 + __log2f(1.0f + exp2f(mn0 - mx0));
      int te = d - uE;
      float nE = ((uE <= U_DIM) && (te >= 0) && (te < T_DIM)) ? r0 : NEG;
      // uO cell
      float bt1 = aO + q.z, lt1 = aE + q.y;
      float mx1 = fmaxf(bt1, lt1), mn1 = fminf(bt1, lt1);
      float r1 = mx1 + __log2f(1.0f + exp2f(mn1 - mx1));
      int to = te - 1;
      float nO = ((uE + 1 <= U_DIM) && (to >= 0) && (to < T_DIM)) ? r1 : NEG;
      aE = nE; aO = nO;
      if (d == dStar) {
        if (uIdx == uE)          ll2 = nE + blkStar;
        else if (uIdx == uE + 1) ll2 = nO + blkStar;
      }
    }
  }
#undef ISSUE

#pragma unroll
  for (int mask = 1; mask < 64; mask <<= 1) ll2 += __shfl_xor(ll2, mask, 64);
  if (lane == 0) llsh[wv] = ll2;
  __syncthreads();
  if (tid == 0)
    outLoss[0] = -(llsh[0] + llsh[1] + llsh[2] + llsh[3]) * 0.25f * LN2;
}

// ---------------- launch
extern "C" void kernel_launch(void* const* d_in, const int* in_sizes, int n_in,
                              void* d_out, int out_size, void* d_ws, size_t ws_size,
                              hipStream_t stream)
{
  const float* enc    = (const float*)d_in[0];
  const float* dec    = (const float*)d_in[1];
  const int*   tokens = (const int*)d_in[2];
  const int*   outLen = (const int*)d_in[3];
  const int*   tokLen = (const int*)d_in[4];
  const float* W1     = (const float*)d_in[5];
  const float* b1     = (const float*)d_in[6];
  const float* W2     = (const float*)d_in[7];
  const float* b2     = (const float*)d_in[8];
  float* out = (float*)d_out;

  char* ws = (char*)d_ws;
  float*   hEnc = (float*)(ws + 0);           // 800*512*4     = 1,638,400
  float*   hDec = (float*)(ws + 1638400);     // 404*512*4     =   827,392
  uchar_t* W2f8 = (uchar_t*)(ws + 2465792);   // 256 regions*2048 = 524,288 (16-aligned)
  float*   pD   = (float*)(ws + 2990080);     // 4*300*128*2*4 = 1,228,800
                                              // + 16KB tail pad for dp chunk-37 overread

  prep_kernel<<<dim3(215), dim3(512), 0, stream>>>(enc, dec, W1, W2, hEnc, hDec, W2f8);
  joint_kernel<<<dim3(26, 17, B_DIM), dim3(256), 0, stream>>>(hEnc, hDec, b1, W2f8, b2, tokens, pD);
  dp_kernel<<<dim3(1), dim3(256), 0, stream>>>(pD, outLen, tokLen, out);
}